// Round 3
// baseline (49.805 us; speedup 1.0000x reference)
//
#include <hip/hip_runtime.h>

typedef __bf16 bf16x8 __attribute__((ext_vector_type(8)));
typedef float  f32x16 __attribute__((ext_vector_type(16)));

#define NI 256
#define NT 256
#define NL 32
#define NE 128
#define HW 49

// Block: 256 threads = 4 waves; wave w owns image ib*4+w (M = 64 pad of 49).
// Grid: 512 = 64 image-groups x 8 text-chunks (32 texts) -> 2 blocks/CU,
// ALL co-resident, identical work, zero tail.
// Staging: T14 split (global->reg early, cvt+ds_write late) + LDS double
// buffer -> ONE barrier per 4-text round; MFMA hides stage latency.
__global__ __launch_bounds__(256, 2)
void clip_match_kernel(const float* __restrict__ img,
                       const float* __restrict__ txt,
                       const int* __restrict__ tlen,
                       const float* __restrict__ nlt,
                       float* __restrict__ out)
{
    const int tid  = threadIdx.x;
    const int wave = tid >> 6;
    const int lane = tid & 63;
    const int ml   = lane & 31;   // m (A rows) / n (B cols) lane index
    const int h    = lane >> 5;   // k-half

    const int tb = blockIdx.x & 7;    // text chunk (32 texts)
    const int ib = blockIdx.x >> 3;   // image group (4 images)
    const int img_i = ib * 4 + wave;

    const float scale = expf(nlt[0]);

    // ---- A fragments: image img_i as [64(pad 49) x 128] bf16, 64 VGPRs ----
    // lane holds A[m = mf*32 + ml, k = ks*16 + h*8 + j]; A[m,k] = img[i,e=k,hw=m]
    bf16x8 afrag[2][8];
    {
        const float* __restrict__ pi = img + (size_t)img_i * (NE * HW);
        #pragma unroll
        for (int mf = 0; mf < 2; ++mf) {
            int m  = mf * 32 + ml;
            int mc = m < HW ? m : HW - 1;   // clamp; pad rows masked in reduce
            #pragma unroll
            for (int ks = 0; ks < 8; ++ks) {
                int kb = ks * 16 + h * 8;
                bf16x8 a;
                #pragma unroll
                for (int j = 0; j < 8; ++j)
                    a[j] = (__bf16)pi[(kb + j) * HW + mc];
                afrag[mf][ks] = a;
            }
        }
    }

    // double-buffered: 2 x (4 texts x 32 l x 128 e) bf16 = 2 x 32 KiB
    __shared__ __align__(16) __bf16 lds[2][4 * NL * NE];

    const float* __restrict__ tsrc0 = txt + (size_t)tb * 32 * NL * NE;

    // ---- prologue: stage round 0 into buffer 0 ----
    {
        const float* __restrict__ src = tsrc0;
        #pragma unroll
        for (int r = 0; r < 8; ++r) {
            int ch = tid + 256 * r;          // 8-float chunk id 0..2047
            const float* p = src + ch * 8;
            float4 f0 = *(const float4*)p;
            float4 f1 = *(const float4*)(p + 4);
            union { __bf16 b[8]; int4 v; } u;
            u.b[0] = (__bf16)f0.x; u.b[1] = (__bf16)f0.y;
            u.b[2] = (__bf16)f0.z; u.b[3] = (__bf16)f0.w;
            u.b[4] = (__bf16)f1.x; u.b[5] = (__bf16)f1.y;
            u.b[6] = (__bf16)f1.z; u.b[7] = (__bf16)f1.w;
            int row = ch >> 4;               // 0..127 (text*32 + l)
            int off = (row * 256 + (ch & 15) * 16) ^ ((row & 15) << 4);
            *(int4*)((char*)lds[0] + off) = u.v;
        }
    }
    __syncthreads();

    int c = 0;
    #pragma unroll 1
    for (int tg = 0; tg < 8; ++tg) {
        // ---- issue next round's global loads early (T14 issue-half) ----
        float4 pf[16];
        if (tg < 7) {
            const float* __restrict__ src = tsrc0 + (size_t)(tg + 1) * 4 * NL * NE;
            #pragma unroll
            for (int r = 0; r < 8; ++r) {
                const float* p = src + (tid + 256 * r) * 8;
                pf[2 * r]     = *(const float4*)p;
                pf[2 * r + 1] = *(const float4*)(p + 4);
            }
        }

        // ---- compute 4 texts from lds[c] ----
        const __bf16* __restrict__ buf = lds[c];
        #pragma unroll 2
        for (int ts = 0; ts < 4; ++ts) {
            const int t = tb * 32 + tg * 4 + ts;
            const float rl = scale / (float)tlen[t];
            // B fragments: lane holds B[k = ks*16+h*8+j, n = ml]
            //            = txt[t, l=ml, e=k]  (same k-map as A)
            bf16x8 bfrag[8];
            {
                int row = ts * NL + ml;
                int sw  = (row & 15) << 4;
                #pragma unroll
                for (int ks = 0; ks < 8; ++ks) {
                    int off = (row * 256 + ks * 32 + h * 16) ^ sw;
                    bfrag[ks] = *(const bf16x8*)((const char*)buf + off);
                }
            }
            f32x16 acc0 = (f32x16)(0.f);
            f32x16 acc1 = (f32x16)(0.f);
            #pragma unroll
            for (int ks = 0; ks < 8; ++ks) {
                acc0 = __builtin_amdgcn_mfma_f32_32x32x16_bf16(
                    afrag[0][ks], bfrag[ks], acc0, 0, 0, 0);
                acc1 = __builtin_amdgcn_mfma_f32_32x32x16_bf16(
                    afrag[1][ks], bfrag[ks], acc1, 0, 0, 0);
            }
            // reduce: max over valid rows (hw), sum over 32 cols (l)
            // C/D (m74/m101): col = lane&31, row r = (reg&3)+8*(reg>>2)+4*h
            float cm = acc0[0];
            #pragma unroll
            for (int r = 1; r < 16; ++r) cm = fmaxf(cm, acc0[r]);
            #pragma unroll
            for (int r = 0; r < 8; ++r)  cm = fmaxf(cm, acc1[r]);
            if (h == 0) cm = fmaxf(cm, acc1[8]);   // m=48, h==0 only

            cm = fmaxf(cm, __shfl_xor(cm, 32));    // merge k-halves (rows)
            float s = cm;                           // col = ml
            s += __shfl_xor(s, 1);
            s += __shfl_xor(s, 2);
            s += __shfl_xor(s, 4);
            s += __shfl_xor(s, 8);
            s += __shfl_xor(s, 16);                 // sum over 32 cols
            if (lane == 0) {
                float v = s * rl;
                out[img_i * NT + t] = v;             // logits_per_image[i,t]
                out[NI * NT + t * NI + img_i] = v;   // logits_per_text[t,i]
            }
        }

        // ---- write-half of staging into the other buffer ----
        if (tg < 7) {
            __bf16* __restrict__ dst = lds[c ^ 1];
            #pragma unroll
            for (int r = 0; r < 8; ++r) {
                int ch = tid + 256 * r;
                float4 f0 = pf[2 * r];
                float4 f1 = pf[2 * r + 1];
                union { __bf16 b[8]; int4 v; } u;
                u.b[0] = (__bf16)f0.x; u.b[1] = (__bf16)f0.y;
                u.b[2] = (__bf16)f0.z; u.b[3] = (__bf16)f0.w;
                u.b[4] = (__bf16)f1.x; u.b[5] = (__bf16)f1.y;
                u.b[6] = (__bf16)f1.z; u.b[7] = (__bf16)f1.w;
                int row = ch >> 4;
                int off = (row * 256 + (ch & 15) * 16) ^ ((row & 15) << 4);
                *(int4*)((char*)dst + off) = u.v;
            }
        }
        __syncthreads();
        c ^= 1;
    }
}

extern "C" void kernel_launch(void* const* d_in, const int* in_sizes, int n_in,
                              void* d_out, int out_size, void* d_ws, size_t ws_size,
                              hipStream_t stream)
{
    const float* img  = (const float*)d_in[0];
    const float* txt  = (const float*)d_in[1];
    const int*   tlen = (const int*)d_in[2];
    const float* nlt  = (const float*)d_in[3];
    float* out = (float*)d_out;
    clip_match_kernel<<<dim3(512), dim3(256), 0, stream>>>(img, txt, tlen, nlt, out);
}

// Round 4
// 45.545 us; speedup vs baseline: 1.0935x; 1.0935x over previous
//
#include <hip/hip_runtime.h>

typedef __bf16 bf16x8 __attribute__((ext_vector_type(8)));
typedef float  f32x16 __attribute__((ext_vector_type(16)));

#define NI 256
#define NT 256
#define NL 32
#define NE 128
#define HW 49
#define NEG_INF (-3.0e38f)

// Block: 256 threads = 4 waves; wave w owns image ib*4+w (M = 64 pad of 49).
// Grid: 512 = 64 image-groups x 8 text-chunks (32 texts) -> 2 blocks/CU.
// Per text: 8 ds_read_b128 (B), 16 MFMA, fmax TREE, one ds_max_f32/lane
// (fire-and-forget). All cross-lane + output work batched in one epilogue.
__global__ __launch_bounds__(256, 2)
void clip_match_kernel(const float* __restrict__ img,
                       const float* __restrict__ txt,
                       const int* __restrict__ tlen,
                       const float* __restrict__ nlt,
                       float* __restrict__ out)
{
    const int tid  = threadIdx.x;
    const int wave = tid >> 6;
    const int lane = tid & 63;
    const int ml   = lane & 31;   // m (A rows) / n (B cols) lane index
    const int h    = lane >> 5;   // k-half

    const int tb = blockIdx.x & 7;    // text chunk (32 texts)
    const int ib = blockIdx.x >> 3;   // image group (4 images)
    const int img_i = ib * 4 + wave;

    const float scale = expf(nlt[0]);

    // double-buffered text staging (2 x 32 KiB) + per-wave colmax scratch
    __shared__ __align__(16) __bf16 lds[2][4 * NL * NE];
    __shared__ __align__(16) float  colmax[4][NL][32];   // [wave][text][col]

    // ---- init colmax to -inf (wave-private region, no barrier needed) ----
    {
        float4 ninf4 = make_float4(NEG_INF, NEG_INF, NEG_INF, NEG_INF);
        float* base = &colmax[wave][0][0];   // 1024 floats per wave
        #pragma unroll
        for (int r = 0; r < 4; ++r)
            *(float4*)(base + lane * 4 + r * 256) = ninf4;
    }

    // ---- A fragments: image img_i as [64(pad 49) x 128] bf16, 64 VGPRs ----
    // lane holds A[m = mf*32 + ml, k = ks*16 + h*8 + j]; A[m,k] = img[i,e=k,hw=m]
    bf16x8 afrag[2][8];
    {
        const float* __restrict__ pi = img + (size_t)img_i * (NE * HW);
        #pragma unroll
        for (int mf = 0; mf < 2; ++mf) {
            int m  = mf * 32 + ml;
            int mc = m < HW ? m : HW - 1;   // clamp; pad rows masked in reduce
            #pragma unroll
            for (int ks = 0; ks < 8; ++ks) {
                int kb = ks * 16 + h * 8;
                bf16x8 a;
                #pragma unroll
                for (int j = 0; j < 8; ++j)
                    a[j] = (__bf16)pi[(kb + j) * HW + mc];
                afrag[mf][ks] = a;
            }
        }
    }

    const float* __restrict__ tsrc0 = txt + (size_t)tb * 32 * NL * NE;

    // ---- prologue: stage round 0 into buffer 0 ----
    {
        #pragma unroll
        for (int r = 0; r < 8; ++r) {
            int ch = tid + 256 * r;          // 8-float chunk id 0..2047
            const float* p = tsrc0 + ch * 8;
            float4 f0 = *(const float4*)p;
            float4 f1 = *(const float4*)(p + 4);
            union { __bf16 b[8]; int4 v; } u;
            u.b[0] = (__bf16)f0.x; u.b[1] = (__bf16)f0.y;
            u.b[2] = (__bf16)f0.z; u.b[3] = (__bf16)f0.w;
            u.b[4] = (__bf16)f1.x; u.b[5] = (__bf16)f1.y;
            u.b[6] = (__bf16)f1.z; u.b[7] = (__bf16)f1.w;
            int row = ch >> 4;               // 0..127 (text*32 + l)
            int off = (row * 256 + (ch & 15) * 16) ^ ((row & 15) << 4);
            *(int4*)((char*)lds[0] + off) = u.v;
        }
    }
    __syncthreads();

    int c = 0;
    #pragma unroll 1
    for (int tg = 0; tg < 8; ++tg) {
        // ---- issue next round's global loads early ----
        float4 pf[16];
        if (tg < 7) {
            const float* __restrict__ src = tsrc0 + (size_t)(tg + 1) * 4 * NL * NE;
            #pragma unroll
            for (int r = 0; r < 8; ++r) {
                const float* p = src + (tid + 256 * r) * 8;
                pf[2 * r]     = *(const float4*)p;
                pf[2 * r + 1] = *(const float4*)(p + 4);
            }
        }

        // ---- compute 4 texts from lds[c] ----
        const __bf16* __restrict__ buf = lds[c];
        #pragma unroll 2
        for (int ts = 0; ts < 4; ++ts) {
            const int tl = tg * 4 + ts;           // text index within chunk
            // B fragments: lane holds B[k = ks*16+h*8+j, n = ml]
            //            = txt[t, l=ml, e=k]  (same k-map as A)
            bf16x8 bfrag[8];
            {
                int row = ts * NL + ml;
                int sw  = (row & 15) << 4;
                #pragma unroll
                for (int ks = 0; ks < 8; ++ks) {
                    int off = (row * 256 + ks * 32 + h * 16) ^ sw;
                    bfrag[ks] = *(const bf16x8*)((const char*)buf + off);
                }
            }
            f32x16 acc0 = (f32x16)(0.f);
            f32x16 acc1 = (f32x16)(0.f);
            #pragma unroll
            for (int ks = 0; ks < 8; ++ks) {
                acc0 = __builtin_amdgcn_mfma_f32_32x32x16_bf16(
                    afrag[0][ks], bfrag[ks], acc0, 0, 0, 0);
                acc1 = __builtin_amdgcn_mfma_f32_32x32x16_bf16(
                    afrag[1][ks], bfrag[ks], acc1, 0, 0, 0);
            }
            // max over valid rows (hw) — pairwise TREE, then one ds_max.
            // C/D (m74/m101): col = lane&31, row r = (reg&3)+8*(reg>>2)+4*h
            // acc0: m = r (all valid). acc1: m = 32+r; regs 0..7 always,
            // reg 8 (r=16 -> m=48) only for h==0.
            float t0[8];
            #pragma unroll
            for (int r = 0; r < 8; ++r) t0[r] = fmaxf(acc0[2*r], acc0[2*r+1]);
            float t1[4];
            #pragma unroll
            for (int r = 0; r < 4; ++r) t1[r] = fmaxf(t0[2*r], t0[2*r+1]);
            float a0m = fmaxf(fmaxf(t1[0], t1[1]), fmaxf(t1[2], t1[3]));
            float u0[4];
            #pragma unroll
            for (int r = 0; r < 4; ++r) u0[r] = fmaxf(acc1[2*r], acc1[2*r+1]);
            float a1m = fmaxf(fmaxf(u0[0], u0[1]), fmaxf(u0[2], u0[3]));
            float ex  = (h == 0) ? acc1[8] : NEG_INF;
            float cm  = fmaxf(fmaxf(a0m, a1m), ex);
            // fire-and-forget: ds_max_f32, no return, no wave stall
            atomicMax(&colmax[wave][tl][ml], cm);
        }

        // ---- write-half of staging into the other buffer ----
        if (tg < 7) {
            __bf16* __restrict__ dst = lds[c ^ 1];
            #pragma unroll
            for (int r = 0; r < 8; ++r) {
                int ch = tid + 256 * r;
                float4 f0 = pf[2 * r];
                float4 f1 = pf[2 * r + 1];
                union { __bf16 b[8]; int4 v; } u;
                u.b[0] = (__bf16)f0.x; u.b[1] = (__bf16)f0.y;
                u.b[2] = (__bf16)f0.z; u.b[3] = (__bf16)f0.w;
                u.b[4] = (__bf16)f1.x; u.b[5] = (__bf16)f1.y;
                u.b[6] = (__bf16)f1.z; u.b[7] = (__bf16)f1.w;
                int row = ch >> 4;
                int off = (row * 256 + (ch & 15) * 16) ^ ((row & 15) << 4);
                *(int4*)((char*)dst + off) = u.v;
            }
        }
        __syncthreads();
        c ^= 1;
    }

    // ---- batched epilogue: sum colmax over 32 cols for all 32 texts ----
    {
        const int t    = lane & 31;    // text within chunk
        const int half = lane >> 5;    // which 16-col slice
        const float* row = &colmax[wave][t][half * 16];
        float4 r0 = *(const float4*)(row + 0);
        float4 r1 = *(const float4*)(row + 4);
        float4 r2 = *(const float4*)(row + 8);
        float4 r3 = *(const float4*)(row + 12);
        float s = ((r0.x + r0.y) + (r0.z + r0.w))
                + ((r1.x + r1.y) + (r1.z + r1.w))
                + ((r2.x + r2.y) + (r2.z + r2.w))
                + ((r3.x + r3.y) + (r3.z + r3.w));
        float tot = s + __shfl_xor(s, 32);         // both halves
        if (half == 0) {
            int tglob = tb * 32 + t;
            float v = tot * scale / (float)tlen[tglob];
            out[img_i * NT + tglob] = v;             // logits_per_image[i,t]
            out[NI * NT + tglob * NI + img_i] = v;   // logits_per_text[t,i]
        }
    }
}

extern "C" void kernel_launch(void* const* d_in, const int* in_sizes, int n_in,
                              void* d_out, int out_size, void* d_ws, size_t ws_size,
                              hipStream_t stream)
{
    const float* img  = (const float*)d_in[0];
    const float* txt  = (const float*)d_in[1];
    const int*   tlen = (const int*)d_in[2];
    const float* nlt  = (const float*)d_in[3];
    float* out = (float*)d_out;
    clip_match_kernel<<<dim3(512), dim3(256), 0, stream>>>(img, txt, tlen, nlt, out);
}